// Round 2
// baseline (442.190 us; speedup 1.0000x reference)
//
#include <hip/hip_runtime.h>
#include <hip/hip_bf16.h>

#define N_NODES 50000
#define N_EDGES 800000
#define N_IN    256
#define N_H     64
#define PAD     32   // ints per node slot (128B line): [0]=deg, [1]=cursor

typedef short short8 __attribute__((ext_vector_type(8)));
typedef float f32x4  __attribute__((ext_vector_type(4)));

__device__ inline short f2bf(float f) {
    __bf16 h = (__bf16)f;
    return (short)__builtin_bit_cast(unsigned short, h);
}
__device__ inline float bflo(unsigned int q) { return __uint_as_float(q << 16); }
__device__ inline float bfhi(unsigned int q) { return __uint_as_float(q & 0xFFFF0000u); }

// ---------------- CSR build (padded atomics: 1 line per node) ----------------

__global__ void k_hist(const int* __restrict__ adj_rows, const int* __restrict__ diff_rows,
                       int* __restrict__ pad) {
    int e = blockIdx.x * 256 + threadIdx.x;
    if (e < N_EDGES) {
        atomicAdd(&pad[(size_t)adj_rows[e] * PAD], 1);
    } else if (e < 2 * N_EDGES) {
        atomicAdd(&pad[((size_t)N_NODES + diff_rows[e - N_EDGES]) * PAD], 1);
    }
}

__global__ void k_scan(int* __restrict__ pad, int* __restrict__ row_ptr) {
    int g = blockIdx.x;
    int* p = pad + (size_t)g * N_NODES * PAD;
    int* rp = row_ptr + g * (N_NODES + 1);
    __shared__ int s[1024];
    int carry = 0;
    for (int base = 0; base < N_NODES; base += 1024) {
        int i = base + (int)threadIdx.x;
        int v = (i < N_NODES) ? p[(size_t)i * PAD] : 0;
        s[threadIdx.x] = v;
        __syncthreads();
        for (int off = 1; off < 1024; off <<= 1) {
            int t = (threadIdx.x >= (unsigned)off) ? s[threadIdx.x - off] : 0;
            __syncthreads();
            s[threadIdx.x] += t;
            __syncthreads();
        }
        int incl = s[threadIdx.x];
        int tot  = s[1023];
        if (i < N_NODES) {
            int ex = carry + incl - v;
            rp[i] = ex;
            p[(size_t)i * PAD + 1] = ex;   // cursor
        }
        carry += tot;
        __syncthreads();
    }
    if (threadIdx.x == 0) rp[N_NODES] = carry;
}

__global__ void k_scatter(const int* __restrict__ adj_rows, const int* __restrict__ adj_cols,
                          const float* __restrict__ adj_w,
                          const int* __restrict__ diff_rows, const int* __restrict__ diff_cols,
                          const float* __restrict__ diff_w,
                          int* __restrict__ pad, int2* __restrict__ csr) {
    int e = blockIdx.x * 256 + threadIdx.x;
    int g, r, c; float w;
    if (e < N_EDGES) {
        g = 0; r = adj_rows[e]; c = adj_cols[e]; w = adj_w[e];
    } else if (e < 2 * N_EDGES) {
        int e2 = e - N_EDGES;
        g = 1; r = diff_rows[e2]; c = diff_cols[e2]; w = diff_w[e2];
    } else return;
    int pos = atomicAdd(&pad[((size_t)g * N_NODES + r) * PAD + 1], 1);
    int2 m; m.x = c; m.y = __float_as_int(w);
    csr[(size_t)g * N_EDGES + pos] = m;
}

// ---------------- GEMM: T[n][128] (bf16), cols 0..63 = Xa@W, 64..127 = Xb@W ----------------

__global__ __launch_bounds__(256) void k_gemm(
    const float* __restrict__ X0, const float* __restrict__ X1,
    const float* __restrict__ X2, const float* __restrict__ X3,
    const float* __restrict__ W1, const float* __restrict__ W2,
    unsigned short* __restrict__ Tadj, unsigned short* __restrict__ Tdiff) {

    const float* X; const float* W; unsigned short* T; int coloff;
    switch (blockIdx.y) {
        case 0:  X = X0; W = W1; T = Tadj;  coloff = 0;  break;  // h1 = bf@W1
        case 1:  X = X2; W = W1; T = Tadj;  coloff = 64; break;  // h3 = shuf_fts@W1
        case 2:  X = X1; W = W2; T = Tdiff; coloff = 0;  break;  // h2 = bl@W2
        default: X = X3; W = W2; T = Tdiff; coloff = 64; break;  // h4 = shuf_fls@W2
    }

    __shared__ __align__(16) unsigned short WT[64][264];
    for (int i = threadIdx.x; i < N_IN * N_H; i += 256) {
        int k = i >> 6, c = i & 63;
        WT[c][k] = (unsigned short)f2bf(W[i]);
    }
    __syncthreads();

    int wid  = threadIdx.x >> 6;
    int lane = threadIdx.x & 63;
    int rb = (blockIdx.x * 4 + wid) * 16;
    if (rb >= N_NODES) return;

    int arow = rb + (lane & 15);
    int kg   = lane >> 4;
    const float* ap = X + (size_t)arow * N_IN + kg * 8;

    f32x4 acc[4];
    for (int ct = 0; ct < 4; ++ct) acc[ct] = (f32x4){0.f, 0.f, 0.f, 0.f};

    for (int kt = 0; kt < 8; ++kt) {
        const float4* p = reinterpret_cast<const float4*>(ap + kt * 32);
        float4 a0 = p[0];
        float4 a1 = p[1];
        short8 af;
        af[0] = f2bf(a0.x); af[1] = f2bf(a0.y); af[2] = f2bf(a0.z); af[3] = f2bf(a0.w);
        af[4] = f2bf(a1.x); af[5] = f2bf(a1.y); af[6] = f2bf(a1.z); af[7] = f2bf(a1.w);
        #pragma unroll
        for (int ct = 0; ct < 4; ++ct) {
            const unsigned short* wp = &WT[ct * 16 + (lane & 15)][kt * 32 + kg * 8];
            short8 bfr = *reinterpret_cast<const short8*>(wp);
            acc[ct] = __builtin_amdgcn_mfma_f32_16x16x32_bf16(af, bfr, acc[ct], 0, 0, 0);
        }
    }

    int rgrp = lane >> 4;
    #pragma unroll
    for (int ct = 0; ct < 4; ++ct) {
        int col = coloff + ct * 16 + (lane & 15);
        #pragma unroll
        for (int r = 0; r < 4; ++r) {
            int row = rb + rgrp * 4 + r;
            T[(size_t)row * 128 + col] = (unsigned short)f2bf(acc[ct][r]);
        }
    }
}

// ---------------- Aggregate (gather) + bias + PReLU, writes final output ----------------

__global__ __launch_bounds__(256) void k_agg(
    const int* __restrict__ row_ptr, const int2* __restrict__ csr,
    const unsigned int* __restrict__ Tadj, const unsigned int* __restrict__ Tdiff,
    const float* __restrict__ b1, const float* __restrict__ a1,
    const float* __restrict__ b2, const float* __restrict__ a2,
    float* __restrict__ out) {

    int wid  = threadIdx.x >> 6;
    int lane = threadIdx.x & 63;
    int node = blockIdx.x * 4 + wid;
    int g    = blockIdx.y;

    const int* rp = row_ptr + g * (N_NODES + 1);
    const int2* el = csr + (size_t)g * N_EDGES;
    const unsigned int* Tu = g ? Tdiff : Tadj;

    int e  = rp[node];
    int e1 = rp[node + 1];
    float ax = 0.f, ay = 0.f;

    for (; e + 4 <= e1; e += 4) {
        int2 m0 = el[e + 0], m1 = el[e + 1], m2 = el[e + 2], m3 = el[e + 3];
        unsigned int q0 = Tu[(size_t)m0.x * 64 + lane];
        unsigned int q1 = Tu[(size_t)m1.x * 64 + lane];
        unsigned int q2 = Tu[(size_t)m2.x * 64 + lane];
        unsigned int q3 = Tu[(size_t)m3.x * 64 + lane];
        float w0 = __int_as_float(m0.y), w1 = __int_as_float(m1.y);
        float w2 = __int_as_float(m2.y), w3 = __int_as_float(m3.y);
        ax += w0 * bflo(q0); ay += w0 * bfhi(q0);
        ax += w1 * bflo(q1); ay += w1 * bfhi(q1);
        ax += w2 * bflo(q2); ay += w2 * bfhi(q2);
        ax += w3 * bflo(q3); ay += w3 * bfhi(q3);
    }
    for (; e < e1; ++e) {
        int2 m = el[e];
        unsigned int q = Tu[(size_t)m.x * 64 + lane];
        float w = __int_as_float(m.y);
        ax += w * bflo(q); ay += w * bfhi(q);
    }

    const float* bias = g ? b2 : b1;
    float slope = g ? a2[0] : a1[0];
    int f = 2 * lane;
    size_t base;
    int fo;
    if (lane < 32) { base = g ? (size_t)3200000 : (size_t)0;       fo = f; }
    else           { base = g ? (size_t)9600000 : (size_t)6400000; fo = f - 64; }
    float v0 = ax + bias[fo];
    float v1 = ay + bias[fo + 1];
    v0 = (v0 >= 0.f) ? v0 : slope * v0;
    v1 = (v1 >= 0.f) ? v1 : slope * v1;
    float2 res; res.x = v0; res.y = v1;
    *reinterpret_cast<float2*>(out + base + (size_t)node * 64 + fo) = res;
}

// ---------------- launch ----------------

extern "C" void kernel_launch(void* const* d_in, const int* in_sizes, int n_in,
                              void* d_out, int out_size, void* d_ws, size_t ws_size,
                              hipStream_t stream) {
    const float* bf_      = (const float*)d_in[0];
    const float* bl_      = (const float*)d_in[1];
    const float* shuf_fts = (const float*)d_in[2];
    const float* shuf_fls = (const float*)d_in[3];
    const int*   adj_rows = (const int*)d_in[4];
    const int*   adj_cols = (const int*)d_in[5];
    const float* adj_w    = (const float*)d_in[6];
    const int*   diff_rows= (const int*)d_in[7];
    const int*   diff_cols= (const int*)d_in[8];
    const float* diff_w   = (const float*)d_in[9];
    const float* W1       = (const float*)d_in[10];
    const float* b1       = (const float*)d_in[11];
    const float* a1       = (const float*)d_in[12];
    const float* W2       = (const float*)d_in[13];
    const float* b2       = (const float*)d_in[14];
    const float* a2       = (const float*)d_in[15];
    float* out = (float*)d_out;

    char* ws = (char*)d_ws;
    // workspace layout (38.8 MB)
    unsigned short* Tadj  = (unsigned short*)(ws);                         // 12.8 MB
    unsigned short* Tdiff = (unsigned short*)(ws + 12800000);              // 12.8 MB
    int2* csr             = (int2*)(ws + 25600000);                        // 12.8 MB
    int*  row_ptr         = (int*)(ws + 38400000);                         // ~400 KB

    // padded deg/cursor lines live in d_out (overwritten by k_agg at the end):
    // 2 * 50000 * 128 B = 12.8 MB  <=  out (51.2 MB)
    int* pad = (int*)d_out;

    hipMemsetAsync(pad, 0, (size_t)2 * N_NODES * PAD * sizeof(int), stream);

    k_hist<<<dim3((2 * N_EDGES + 255) / 256), dim3(256), 0, stream>>>(adj_rows, diff_rows, pad);
    k_scan<<<dim3(2), dim3(1024), 0, stream>>>(pad, row_ptr);
    k_scatter<<<dim3((2 * N_EDGES + 255) / 256), dim3(256), 0, stream>>>(
        adj_rows, adj_cols, adj_w, diff_rows, diff_cols, diff_w, pad, csr);

    k_gemm<<<dim3((N_NODES + 63) / 64, 4), dim3(256), 0, stream>>>(
        bf_, bl_, shuf_fts, shuf_fls, W1, W2, Tadj, Tdiff);

    k_agg<<<dim3(N_NODES / 4, 2), dim3(256), 0, stream>>>(
        row_ptr, csr, (const unsigned int*)Tadj, (const unsigned int*)Tdiff,
        b1, a1, b2, a2, out);
}

// Round 3
// 297.012 us; speedup vs baseline: 1.4888x; 1.4888x over previous
//
#include <hip/hip_runtime.h>
#include <hip/hip_bf16.h>

#define N_NODES 50000
#define N_EDGES 800000
#define N_IN    256
#define N_H     64
#define PAD     32   // ints per node slot (128B line): [0]=deg, [1]=cursor
#define CH      512  // nodes per scan block
#define BLKS    98   // ceil(N_NODES / CH)

typedef short short8 __attribute__((ext_vector_type(8)));
typedef float f32x4  __attribute__((ext_vector_type(4)));

__device__ inline short f2bf(float f) {
    __bf16 h = (__bf16)f;
    return (short)__builtin_bit_cast(unsigned short, h);
}
__device__ inline float bflo(unsigned int q) { return __uint_as_float(q << 16); }
__device__ inline float bfhi(unsigned int q) { return __uint_as_float(q & 0xFFFF0000u); }

// ---------------- CSR build (padded atomics: 1 line per node) ----------------

__global__ void k_hist(const int* __restrict__ adj_rows, const int* __restrict__ diff_rows,
                       int* __restrict__ pad) {
    int e = blockIdx.x * 256 + threadIdx.x;
    if (e < N_EDGES) {
        atomicAdd(&pad[(size_t)adj_rows[e] * PAD], 1);
    } else if (e < 2 * N_EDGES) {
        atomicAdd(&pad[((size_t)N_NODES + diff_rows[e - N_EDGES]) * PAD], 1);
    }
}

// phase A: per-block partial sums of degrees
__global__ __launch_bounds__(256) void k_part(const int* __restrict__ pad, int* __restrict__ bs) {
    int g = blockIdx.y, bx = blockIdx.x, t = threadIdx.x;
    const int* p = pad + (size_t)g * N_NODES * PAD;
    int i0 = bx * CH + 2 * t, i1 = i0 + 1;
    int v0 = (i0 < N_NODES) ? p[(size_t)i0 * PAD] : 0;
    int v1 = (i1 < N_NODES) ? p[(size_t)i1 * PAD] : 0;
    __shared__ int s[256];
    s[t] = v0 + v1;
    __syncthreads();
    for (int off = 128; off > 0; off >>= 1) {
        if (t < off) s[t] += s[t + off];
        __syncthreads();
    }
    if (t == 0) bs[g * BLKS + bx] = s[0];
}

// phase B: scan the block sums (both graphs in one 256-thread block)
__global__ __launch_bounds__(256) void k_mid(int* __restrict__ bs, int* __restrict__ row_ptr) {
    int t = threadIdx.x;
    int g = t >> 7, b = t & 127;
    int v0 = (b < BLKS) ? bs[g * BLKS + b] : 0;
    __shared__ int s[256];
    s[t] = v0;
    __syncthreads();
    for (int off = 1; off < 128; off <<= 1) {
        int v = (b >= off) ? s[t - off] : 0;
        __syncthreads();
        s[t] += v;
        __syncthreads();
    }
    int excl = s[t] - v0;
    if (b < BLKS) bs[g * BLKS + b] = excl;
    if (t == 0) {
        row_ptr[N_NODES] = N_EDGES;
        row_ptr[(N_NODES + 1) + N_NODES] = N_EDGES;
    }
}

// phase C: local scan + global offset -> row_ptr and cursor
__global__ __launch_bounds__(256) void k_final(int* __restrict__ pad, const int* __restrict__ bs,
                                               int* __restrict__ row_ptr) {
    int g = blockIdx.y, bx = blockIdx.x, t = threadIdx.x;
    int* p = pad + (size_t)g * N_NODES * PAD;
    int* rp = row_ptr + g * (N_NODES + 1);
    int base = bs[g * BLKS + bx];
    int i0 = bx * CH + 2 * t, i1 = i0 + 1;
    int v0 = (i0 < N_NODES) ? p[(size_t)i0 * PAD] : 0;
    int v1 = (i1 < N_NODES) ? p[(size_t)i1 * PAD] : 0;
    int local = v0 + v1;
    __shared__ int s[256];
    s[t] = local;
    __syncthreads();
    for (int off = 1; off < 256; off <<= 1) {
        int v = (t >= off) ? s[t - off] : 0;
        __syncthreads();
        s[t] += v;
        __syncthreads();
    }
    int excl = s[t] - local;
    int e0 = base + excl, e1 = e0 + v0;
    if (i0 < N_NODES) { rp[i0] = e0; p[(size_t)i0 * PAD + 1] = e0; }
    if (i1 < N_NODES) { rp[i1] = e1; p[(size_t)i1 * PAD + 1] = e1; }
}

__global__ void k_scatter(const int* __restrict__ adj_rows, const int* __restrict__ adj_cols,
                          const float* __restrict__ adj_w,
                          const int* __restrict__ diff_rows, const int* __restrict__ diff_cols,
                          const float* __restrict__ diff_w,
                          int* __restrict__ pad, int2* __restrict__ csr) {
    int e = blockIdx.x * 256 + threadIdx.x;
    int g, r, c; float w;
    if (e < N_EDGES) {
        g = 0; r = adj_rows[e]; c = adj_cols[e]; w = adj_w[e];
    } else if (e < 2 * N_EDGES) {
        int e2 = e - N_EDGES;
        g = 1; r = diff_rows[e2]; c = diff_cols[e2]; w = diff_w[e2];
    } else return;
    int pos = atomicAdd(&pad[((size_t)g * N_NODES + r) * PAD + 1], 1);
    int2 m; m.x = c; m.y = __float_as_int(w);
    csr[(size_t)g * N_EDGES + pos] = m;
}

// ---------------- GEMM: T[n][128] (bf16), cols 0..63 = Xa@W, 64..127 = Xb@W ----------------

__global__ __launch_bounds__(256) void k_gemm(
    const float* __restrict__ X0, const float* __restrict__ X1,
    const float* __restrict__ X2, const float* __restrict__ X3,
    const float* __restrict__ W1, const float* __restrict__ W2,
    unsigned short* __restrict__ Tadj, unsigned short* __restrict__ Tdiff) {

    const float* X; const float* W; unsigned short* T; int coloff;
    switch (blockIdx.y) {
        case 0:  X = X0; W = W1; T = Tadj;  coloff = 0;  break;  // h1 = bf@W1
        case 1:  X = X2; W = W1; T = Tadj;  coloff = 64; break;  // h3 = shuf_fts@W1
        case 2:  X = X1; W = W2; T = Tdiff; coloff = 0;  break;  // h2 = bl@W2
        default: X = X3; W = W2; T = Tdiff; coloff = 64; break;  // h4 = shuf_fls@W2
    }

    __shared__ __align__(16) unsigned short WT[64][264];
    for (int i = threadIdx.x; i < N_IN * N_H; i += 256) {
        int k = i >> 6, c = i & 63;
        WT[c][k] = (unsigned short)f2bf(W[i]);
    }
    __syncthreads();

    int wid  = threadIdx.x >> 6;
    int lane = threadIdx.x & 63;
    int rb = (blockIdx.x * 4 + wid) * 16;
    if (rb >= N_NODES) return;

    int arow = rb + (lane & 15);
    int kg   = lane >> 4;
    const float* ap = X + (size_t)arow * N_IN + kg * 8;

    f32x4 acc[4];
    for (int ct = 0; ct < 4; ++ct) acc[ct] = (f32x4){0.f, 0.f, 0.f, 0.f};

    for (int kt = 0; kt < 8; ++kt) {
        const float4* p = reinterpret_cast<const float4*>(ap + kt * 32);
        float4 a0 = p[0];
        float4 a1 = p[1];
        short8 af;
        af[0] = f2bf(a0.x); af[1] = f2bf(a0.y); af[2] = f2bf(a0.z); af[3] = f2bf(a0.w);
        af[4] = f2bf(a1.x); af[5] = f2bf(a1.y); af[6] = f2bf(a1.z); af[7] = f2bf(a1.w);
        #pragma unroll
        for (int ct = 0; ct < 4; ++ct) {
            const unsigned short* wp = &WT[ct * 16 + (lane & 15)][kt * 32 + kg * 8];
            short8 bfr = *reinterpret_cast<const short8*>(wp);
            acc[ct] = __builtin_amdgcn_mfma_f32_16x16x32_bf16(af, bfr, acc[ct], 0, 0, 0);
        }
    }

    int rgrp = lane >> 4;
    #pragma unroll
    for (int ct = 0; ct < 4; ++ct) {
        int col = coloff + ct * 16 + (lane & 15);
        #pragma unroll
        for (int r = 0; r < 4; ++r) {
            int row = rb + rgrp * 4 + r;
            T[(size_t)row * 128 + col] = (unsigned short)f2bf(acc[ct][r]);
        }
    }
}

// ---------------- Aggregate (gather) + bias + PReLU, writes final output ----------------

__global__ __launch_bounds__(256) void k_agg(
    const int* __restrict__ row_ptr, const int2* __restrict__ csr,
    const unsigned int* __restrict__ Tadj, const unsigned int* __restrict__ Tdiff,
    const float* __restrict__ b1, const float* __restrict__ a1,
    const float* __restrict__ b2, const float* __restrict__ a2,
    float* __restrict__ out) {

    int wid  = threadIdx.x >> 6;
    int lane = threadIdx.x & 63;
    int node = blockIdx.x * 4 + wid;
    int g    = blockIdx.y;

    const int* rp = row_ptr + g * (N_NODES + 1);
    const int2* el = csr + (size_t)g * N_EDGES;
    const unsigned int* Tu = g ? Tdiff : Tadj;

    int e  = rp[node];
    int e1 = rp[node + 1];
    float ax = 0.f, ay = 0.f;

    for (; e + 4 <= e1; e += 4) {
        int2 m0 = el[e + 0], m1 = el[e + 1], m2 = el[e + 2], m3 = el[e + 3];
        unsigned int q0 = Tu[(size_t)m0.x * 64 + lane];
        unsigned int q1 = Tu[(size_t)m1.x * 64 + lane];
        unsigned int q2 = Tu[(size_t)m2.x * 64 + lane];
        unsigned int q3 = Tu[(size_t)m3.x * 64 + lane];
        float w0 = __int_as_float(m0.y), w1 = __int_as_float(m1.y);
        float w2 = __int_as_float(m2.y), w3 = __int_as_float(m3.y);
        ax += w0 * bflo(q0); ay += w0 * bfhi(q0);
        ax += w1 * bflo(q1); ay += w1 * bfhi(q1);
        ax += w2 * bflo(q2); ay += w2 * bfhi(q2);
        ax += w3 * bflo(q3); ay += w3 * bfhi(q3);
    }
    for (; e < e1; ++e) {
        int2 m = el[e];
        unsigned int q = Tu[(size_t)m.x * 64 + lane];
        float w = __int_as_float(m.y);
        ax += w * bflo(q); ay += w * bfhi(q);
    }

    const float* bias = g ? b2 : b1;
    float slope = g ? a2[0] : a1[0];
    int f = 2 * lane;
    size_t base;
    int fo;
    if (lane < 32) { base = g ? (size_t)3200000 : (size_t)0;       fo = f; }
    else           { base = g ? (size_t)9600000 : (size_t)6400000; fo = f - 64; }
    float v0 = ax + bias[fo];
    float v1 = ay + bias[fo + 1];
    v0 = (v0 >= 0.f) ? v0 : slope * v0;
    v1 = (v1 >= 0.f) ? v1 : slope * v1;
    float2 res; res.x = v0; res.y = v1;
    *reinterpret_cast<float2*>(out + base + (size_t)node * 64 + fo) = res;
}

// ---------------- launch ----------------

extern "C" void kernel_launch(void* const* d_in, const int* in_sizes, int n_in,
                              void* d_out, int out_size, void* d_ws, size_t ws_size,
                              hipStream_t stream) {
    const float* bf_      = (const float*)d_in[0];
    const float* bl_      = (const float*)d_in[1];
    const float* shuf_fts = (const float*)d_in[2];
    const float* shuf_fls = (const float*)d_in[3];
    const int*   adj_rows = (const int*)d_in[4];
    const int*   adj_cols = (const int*)d_in[5];
    const float* adj_w    = (const float*)d_in[6];
    const int*   diff_rows= (const int*)d_in[7];
    const int*   diff_cols= (const int*)d_in[8];
    const float* diff_w   = (const float*)d_in[9];
    const float* W1       = (const float*)d_in[10];
    const float* b1       = (const float*)d_in[11];
    const float* a1       = (const float*)d_in[12];
    const float* W2       = (const float*)d_in[13];
    const float* b2       = (const float*)d_in[14];
    const float* a2       = (const float*)d_in[15];
    float* out = (float*)d_out;

    char* ws = (char*)d_ws;
    // workspace layout
    unsigned short* Tadj  = (unsigned short*)(ws);                         // 12.8 MB
    unsigned short* Tdiff = (unsigned short*)(ws + 12800000);              // 12.8 MB
    int2* csr             = (int2*)(ws + 25600000);                        // 12.8 MB
    int*  row_ptr         = (int*)(ws + 38400000);                         // ~400 KB
    int*  bs              = (int*)(ws + 38801024);                         // 196 ints

    // padded deg/cursor lines live in d_out (overwritten by k_agg at the end)
    int* pad = (int*)d_out;

    hipMemsetAsync(pad, 0, (size_t)2 * N_NODES * PAD * sizeof(int), stream);

    k_hist<<<dim3((2 * N_EDGES + 255) / 256), dim3(256), 0, stream>>>(adj_rows, diff_rows, pad);
    k_part<<<dim3(BLKS, 2), dim3(256), 0, stream>>>(pad, bs);
    k_mid<<<dim3(1), dim3(256), 0, stream>>>(bs, row_ptr);
    k_final<<<dim3(BLKS, 2), dim3(256), 0, stream>>>(pad, bs, row_ptr);
    k_scatter<<<dim3((2 * N_EDGES + 255) / 256), dim3(256), 0, stream>>>(
        adj_rows, adj_cols, adj_w, diff_rows, diff_cols, diff_w, pad, csr);

    k_gemm<<<dim3((N_NODES + 63) / 64, 4), dim3(256), 0, stream>>>(
        bf_, bl_, shuf_fts, shuf_fls, W1, W2, Tadj, Tdiff);

    k_agg<<<dim3(N_NODES / 4, 2), dim3(256), 0, stream>>>(
        row_ptr, csr, (const unsigned int*)Tadj, (const unsigned int*)Tdiff,
        b1, a1, b2, a2, out);
}

// Round 4
// 193.591 us; speedup vs baseline: 2.2841x; 1.5342x over previous
//
#include <hip/hip_runtime.h>
#include <hip/hip_bf16.h>

#define N_NODES 50000
#define N_EDGES 800000
#define N_IN    256
#define N_H     64
#define NB      125    // buckets per graph
#define RPB     400    // rows per bucket (NB*RPB == N_NODES)
#define BCAP    8192   // bucket capacity (mean 6400, sigma ~80)
#define EPT     8      // edges per thread in k_bin
#define BIN_BLK 2048   // edges per k_bin block

typedef short short8 __attribute__((ext_vector_type(8)));
typedef float f32x4  __attribute__((ext_vector_type(4)));

__device__ inline short f2bf(float f) {
    __bf16 h = (__bf16)f;
    return (short)__builtin_bit_cast(unsigned short, h);
}
__device__ inline float bflo(unsigned int q) { return __uint_as_float(q << 16); }
__device__ inline float bfhi(unsigned int q) { return __uint_as_float(q & 0xFFFF0000u); }

// ---------------- phase 1: bin edges by row range ----------------

__global__ __launch_bounds__(256) void k_bin(
    const int* __restrict__ adj_rows, const int* __restrict__ adj_cols,
    const float* __restrict__ adj_w,
    const int* __restrict__ diff_rows, const int* __restrict__ diff_cols,
    const float* __restrict__ diff_w,
    int* __restrict__ gcnt, int2* __restrict__ bin) {

    int g = blockIdx.y;
    const int*   rows = g ? diff_rows : adj_rows;
    const int*   cols = g ? diff_cols : adj_cols;
    const float* ww   = g ? diff_w    : adj_w;
    int base_e = blockIdx.x * BIN_BLK;
    int t = threadIdx.x;

    __shared__ int lcnt[NB];
    __shared__ int lbase[NB];
    for (int i = t; i < NB; i += 256) lcnt[i] = 0;
    __syncthreads();

    int lpos[EPT];
    int bkt[EPT];
    #pragma unroll
    for (int e = 0; e < EPT; ++e) {
        int idx = base_e + e * 256 + t;
        if (idx < N_EDGES) {
            int r = rows[idx];
            int b = r / RPB;
            bkt[e] = b;
            lpos[e] = atomicAdd(&lcnt[b], 1);
        } else bkt[e] = -1;
    }
    __syncthreads();
    for (int i = t; i < NB; i += 256) lbase[i] = atomicAdd(&gcnt[g * NB + i], lcnt[i]);
    __syncthreads();

    #pragma unroll
    for (int e = 0; e < EPT; ++e) {
        int idx = base_e + e * 256 + t;
        if (idx < N_EDGES) {
            unsigned int r = (unsigned int)rows[idx];
            unsigned int c = (unsigned int)cols[idx];
            int b = bkt[e];
            int2 m;
            m.x = (int)((r << 16) | c);
            m.y = __float_as_int(ww[idx]);
            bin[((size_t)(g * NB + b)) * BCAP + lbase[b] + lpos[e]] = m;
        }
    }
}

// ---------------- phase 2: per-bucket CSR build (hist + scan + local scatter) ----------------

__global__ __launch_bounds__(256) void k_build(
    const int* __restrict__ gcnt, const int2* __restrict__ bin,
    int2* __restrict__ csr, int* __restrict__ row_ptr) {

    int g = blockIdx.y, b = blockIdx.x, t = threadIdx.x;
    __shared__ int hist[512];
    __shared__ int s2[256];
    __shared__ int sbase;

    for (int i = t; i < 512; i += 256) hist[i] = 0;
    __syncthreads();

    int cnt = gcnt[g * NB + b];
    const int2* be = bin + ((size_t)(g * NB + b)) * BCAP;
    int r0 = b * RPB;

    for (int i = t; i < cnt; i += 256) {
        unsigned int rc = (unsigned int)be[i].x;
        atomicAdd(&hist[(rc >> 16) - r0], 1);
    }
    __syncthreads();

    if (t == 0) {
        int s = 0;
        for (int i = 0; i < b; ++i) s += gcnt[g * NB + i];
        sbase = s;
    }

    int v0 = hist[2 * t], v1 = hist[2 * t + 1];
    int local = v0 + v1;
    s2[t] = local;
    __syncthreads();
    for (int off = 1; off < 256; off <<= 1) {
        int v = (t >= off) ? s2[t - off] : 0;
        __syncthreads();
        s2[t] += v;
        __syncthreads();
    }
    int e0 = sbase + (s2[t] - local);   // exclusive prefix of element 2t (+ bucket base)
    int e1 = e0 + v0;

    int* rp = row_ptr + g * (N_NODES + 1);
    if (2 * t < RPB)     rp[r0 + 2 * t]     = e0;
    if (2 * t + 1 < RPB) rp[r0 + 2 * t + 1] = e1;
    __syncthreads();
    hist[2 * t] = e0;
    hist[2 * t + 1] = e1;
    __syncthreads();

    int2* cg = csr + (size_t)g * N_EDGES;
    for (int i = t; i < cnt; i += 256) {
        int2 m = be[i];
        unsigned int rc = (unsigned int)m.x;
        int lr = (int)(rc >> 16) - r0;
        int pos = atomicAdd(&hist[lr], 1);
        int2 o;
        o.x = (int)(rc & 0xFFFFu);
        o.y = m.y;
        cg[pos] = o;
    }
    if (b == NB - 1 && t == 0) rp[N_NODES] = N_EDGES;
}

// ---------------- GEMM: T[n][128] (bf16), cols 0..63 = Xa@W, 64..127 = Xb@W ----------------

__global__ __launch_bounds__(256) void k_gemm(
    const float* __restrict__ X0, const float* __restrict__ X1,
    const float* __restrict__ X2, const float* __restrict__ X3,
    const float* __restrict__ W1, const float* __restrict__ W2,
    unsigned short* __restrict__ Tadj, unsigned short* __restrict__ Tdiff) {

    const float* X; const float* W; unsigned short* T; int coloff;
    switch (blockIdx.y) {
        case 0:  X = X0; W = W1; T = Tadj;  coloff = 0;  break;  // h1 = bf@W1
        case 1:  X = X2; W = W1; T = Tadj;  coloff = 64; break;  // h3 = shuf_fts@W1
        case 2:  X = X1; W = W2; T = Tdiff; coloff = 0;  break;  // h2 = bl@W2
        default: X = X3; W = W2; T = Tdiff; coloff = 64; break;  // h4 = shuf_fls@W2
    }

    __shared__ __align__(16) unsigned short WT[64][264];
    for (int i = threadIdx.x; i < N_IN * N_H; i += 256) {
        int k = i >> 6, c = i & 63;
        WT[c][k] = (unsigned short)f2bf(W[i]);
    }
    __syncthreads();

    int wid  = threadIdx.x >> 6;
    int lane = threadIdx.x & 63;
    int rb = (blockIdx.x * 4 + wid) * 16;
    if (rb >= N_NODES) return;

    int arow = rb + (lane & 15);
    int kg   = lane >> 4;
    const float* ap = X + (size_t)arow * N_IN + kg * 8;

    f32x4 acc[4];
    for (int ct = 0; ct < 4; ++ct) acc[ct] = (f32x4){0.f, 0.f, 0.f, 0.f};

    for (int kt = 0; kt < 8; ++kt) {
        const float4* p = reinterpret_cast<const float4*>(ap + kt * 32);
        float4 a0 = p[0];
        float4 a1 = p[1];
        short8 af;
        af[0] = f2bf(a0.x); af[1] = f2bf(a0.y); af[2] = f2bf(a0.z); af[3] = f2bf(a0.w);
        af[4] = f2bf(a1.x); af[5] = f2bf(a1.y); af[6] = f2bf(a1.z); af[7] = f2bf(a1.w);
        #pragma unroll
        for (int ct = 0; ct < 4; ++ct) {
            const unsigned short* wp = &WT[ct * 16 + (lane & 15)][kt * 32 + kg * 8];
            short8 bfr = *reinterpret_cast<const short8*>(wp);
            acc[ct] = __builtin_amdgcn_mfma_f32_16x16x32_bf16(af, bfr, acc[ct], 0, 0, 0);
        }
    }

    int rgrp = lane >> 4;
    #pragma unroll
    for (int ct = 0; ct < 4; ++ct) {
        int col = coloff + ct * 16 + (lane & 15);
        #pragma unroll
        for (int r = 0; r < 4; ++r) {
            int row = rb + rgrp * 4 + r;
            T[(size_t)row * 128 + col] = (unsigned short)f2bf(acc[ct][r]);
        }
    }
}

// ---------------- Aggregate (gather) + bias + PReLU, writes final output ----------------

__global__ __launch_bounds__(256) void k_agg(
    const int* __restrict__ row_ptr, const int2* __restrict__ csr,
    const unsigned int* __restrict__ Tadj, const unsigned int* __restrict__ Tdiff,
    const float* __restrict__ b1, const float* __restrict__ a1,
    const float* __restrict__ b2, const float* __restrict__ a2,
    float* __restrict__ out) {

    int wid  = threadIdx.x >> 6;
    int lane = threadIdx.x & 63;
    int node = blockIdx.x * 4 + wid;
    int g    = blockIdx.y;

    const int* rp = row_ptr + g * (N_NODES + 1);
    const int2* el = csr + (size_t)g * N_EDGES;
    const unsigned int* Tu = g ? Tdiff : Tadj;

    int e  = rp[node];
    int e1 = rp[node + 1];
    float ax = 0.f, ay = 0.f;

    for (; e + 4 <= e1; e += 4) {
        int2 m0 = el[e + 0], m1 = el[e + 1], m2 = el[e + 2], m3 = el[e + 3];
        unsigned int q0 = Tu[(size_t)m0.x * 64 + lane];
        unsigned int q1 = Tu[(size_t)m1.x * 64 + lane];
        unsigned int q2 = Tu[(size_t)m2.x * 64 + lane];
        unsigned int q3 = Tu[(size_t)m3.x * 64 + lane];
        float w0 = __int_as_float(m0.y), w1 = __int_as_float(m1.y);
        float w2 = __int_as_float(m2.y), w3 = __int_as_float(m3.y);
        ax += w0 * bflo(q0); ay += w0 * bfhi(q0);
        ax += w1 * bflo(q1); ay += w1 * bfhi(q1);
        ax += w2 * bflo(q2); ay += w2 * bfhi(q2);
        ax += w3 * bflo(q3); ay += w3 * bfhi(q3);
    }
    for (; e < e1; ++e) {
        int2 m = el[e];
        unsigned int q = Tu[(size_t)m.x * 64 + lane];
        float w = __int_as_float(m.y);
        ax += w * bflo(q); ay += w * bfhi(q);
    }

    const float* bias = g ? b2 : b1;
    float slope = g ? a2[0] : a1[0];
    int f = 2 * lane;
    size_t base;
    int fo;
    if (lane < 32) { base = g ? (size_t)3200000 : (size_t)0;       fo = f; }
    else           { base = g ? (size_t)9600000 : (size_t)6400000; fo = f - 64; }
    float v0 = ax + bias[fo];
    float v1 = ay + bias[fo + 1];
    v0 = (v0 >= 0.f) ? v0 : slope * v0;
    v1 = (v1 >= 0.f) ? v1 : slope * v1;
    float2 res; res.x = v0; res.y = v1;
    *reinterpret_cast<float2*>(out + base + (size_t)node * 64 + fo) = res;
}

// ---------------- launch ----------------

extern "C" void kernel_launch(void* const* d_in, const int* in_sizes, int n_in,
                              void* d_out, int out_size, void* d_ws, size_t ws_size,
                              hipStream_t stream) {
    const float* bf_      = (const float*)d_in[0];
    const float* bl_      = (const float*)d_in[1];
    const float* shuf_fts = (const float*)d_in[2];
    const float* shuf_fls = (const float*)d_in[3];
    const int*   adj_rows = (const int*)d_in[4];
    const int*   adj_cols = (const int*)d_in[5];
    const float* adj_w    = (const float*)d_in[6];
    const int*   diff_rows= (const int*)d_in[7];
    const int*   diff_cols= (const int*)d_in[8];
    const float* diff_w   = (const float*)d_in[9];
    const float* W1       = (const float*)d_in[10];
    const float* b1       = (const float*)d_in[11];
    const float* a1       = (const float*)d_in[12];
    const float* W2       = (const float*)d_in[13];
    const float* b2       = (const float*)d_in[14];
    const float* a2       = (const float*)d_in[15];
    float* out = (float*)d_out;

    char* ws = (char*)d_ws;
    // workspace layout (~38.8 MB)
    unsigned short* Tadj  = (unsigned short*)(ws);                         // 12.8 MB
    unsigned short* Tdiff = (unsigned short*)(ws + 12800000);              // 12.8 MB
    int2* csr             = (int2*)(ws + 25600000);                        // 12.8 MB
    int*  row_ptr         = (int*)(ws + 38400000);                         // 400 KB
    int*  gcnt            = (int*)(ws + 38801024);                         // 250 ints

    // bin buckets live in d_out (16.4 MB <= 51.2 MB), dead before k_agg writes output
    int2* bin = (int2*)d_out;

    hipMemsetAsync(gcnt, 0, 2 * NB * sizeof(int), stream);

    k_bin<<<dim3((N_EDGES + BIN_BLK - 1) / BIN_BLK, 2), dim3(256), 0, stream>>>(
        adj_rows, adj_cols, adj_w, diff_rows, diff_cols, diff_w, gcnt, bin);
    k_build<<<dim3(NB, 2), dim3(256), 0, stream>>>(gcnt, bin, csr, row_ptr);

    k_gemm<<<dim3((N_NODES + 63) / 64, 4), dim3(256), 0, stream>>>(
        bf_, bl_, shuf_fts, shuf_fls, W1, W2, Tadj, Tdiff);

    k_agg<<<dim3(N_NODES / 4, 2), dim3(256), 0, stream>>>(
        row_ptr, csr, (const unsigned int*)Tadj, (const unsigned int*)Tdiff,
        b1, a1, b2, a2, out);
}